// Round 20
// baseline (87.944 us; speedup 1.0000x reference)
//
#include <hip/hip_runtime.h>
#include <cstdint>
#include <cstddef>

// Problem constants (from reference): N=16384, D=256.
#define NV 16384
#define DD 256
#define TPB 1024           // k_mis threads (16 waves); thread t owns v = t + 1024k
#define NGRP 16            // groups per thread
#define LCAP 23            // lower-neighbor cap in pend (fallback: sorted-row walk)

// compiler memory barrier: forces LDS re-reads across spin iterations WITHOUT
// ordering the loads within one iteration against each other
#define CFENCE() asm volatile("" ::: "memory")

// ---------------------------------------------------------------------------
// K_prep: nbr rows are SORTED ascending (np.unique in the ref), so the lower
// neighbors of v are exactly the row prefix row[0..nlo). Store count + up to
// 23 u16 global ids in 3 uint4 per vertex:
//   W0 = min(nlo,0xffff) | e0<<16 ; W1 = e1|e2<<16 ; ... ; W11 = e21|e22<<16
// ---------------------------------------------------------------------------
__global__ __launch_bounds__(256)
void k_prep(const int* __restrict__ nbr, const int* __restrict__ deg,
            int maxdeg, int n, uint4* __restrict__ pend_g)
{
    int v = blockIdx.x * 256 + threadIdx.x;
    if (v >= n) return;
    const int dv = deg[v];
    const int* __restrict__ row = nbr + (size_t)v * (size_t)maxdeg;
    int nlo = 0;
    while (nlo < dv && row[nlo] < v) ++nlo;

    unsigned w0=0,w1=0,w2=0,w3=0,w4=0,w5=0,w6=0,w7=0,w8=0,w9=0,w10=0,w11=0;
    const int m = nlo > LCAP ? LCAP : nlo;
    for (int i = 0; i < m; ++i) {
        unsigned e = (unsigned)row[i];
        switch (i) {
            case 0:  w0  |= e << 16; break;
            case 1:  w1  |= e; break;   case 2:  w1  |= e << 16; break;
            case 3:  w2  |= e; break;   case 4:  w2  |= e << 16; break;
            case 5:  w3  |= e; break;   case 6:  w3  |= e << 16; break;
            case 7:  w4  |= e; break;   case 8:  w4  |= e << 16; break;
            case 9:  w5  |= e; break;   case 10: w5  |= e << 16; break;
            case 11: w6  |= e; break;   case 12: w6  |= e << 16; break;
            case 13: w7  |= e; break;   case 14: w7  |= e << 16; break;
            case 15: w8  |= e; break;   case 16: w8  |= e << 16; break;
            case 17: w9  |= e; break;   case 18: w9  |= e << 16; break;
            case 19: w10 |= e; break;   case 20: w10 |= e << 16; break;
            case 21: w11 |= e; break;   case 22: w11 |= e << 16; break;
        }
    }
    w0 |= (unsigned)(nlo > 0xffff ? 0xffff : nlo);
    pend_g[3 * (size_t)v]     = make_uint4(w0, w1, w2, w3);
    pend_g[3 * (size_t)v + 1] = make_uint4(w4, w5, w6, w7);
    pend_g[3 * (size_t)v + 2] = make_uint4(w8, w9, w10, w11);
}

// ---------------------------------------------------------------------------
// K_mis: lexicographic greedy MIS, single WG of 16 waves, ZERO barriers in
// the main loop — fully asynchronous wave-dataflow. PURE PULL:
//   st[v]: 0=unknown, 1=head, 2=nonhead. ONE writer per byte (v itself).
//   Thread t owns v = t + 1024k (k=0..15). Each wave spins until all its 64
//   current vertices decide (probing ONLY their own lower-nbr statuses),
//   then advances — no block convergence, no barrier, no flag protocol.
// Progress proof: the globally smallest undecided vertex has all deps
// decided; its owner wave must be at exactly that group (earlier groups all
// decided by minimality), so its next spin iteration decides it.
// s_sleep(1) after the first failed iteration keeps spinning waves from
// saturating the CU's LDS pipe. Epilogue syncs once.
// ---------------------------------------------------------------------------
__global__ __launch_bounds__(TPB, 4)
void k_mis(const int* __restrict__ nbr, const int* __restrict__ deg,
           int maxdeg, int n, const uint4* __restrict__ pend_g,
           int* __restrict__ headlist, float* __restrict__ out_tail)
{
    __shared__ __align__(16) unsigned char st[NV];
    __shared__ int s_ws[TPB / 64];
    const int t    = threadIdx.x;
    const int lane = t & 63;
    const int wid  = t >> 6;

    ((uint4*)st)[t] = make_uint4(0u, 0u, 0u, 0u);   // 1024*16B == NV
    __syncthreads();                                 // the only pre-epilogue barrier

    // prefetch group 0 pend (3 x uint4), double-buffered across groups
    uint4 pa = make_uint4(0,0,0,0), pb = pa, pc = pa;
    if (t < n) {
        pa = pend_g[3 * (size_t)t];
        pb = pend_g[3 * (size_t)t + 1];
        pc = pend_g[3 * (size_t)t + 2];
    }

    for (int k = 0; k < NGRP; ++k) {
        const int v = t + 1024 * k;
        // prefetch next group's pend; stays in flight during the spin
        uint4 qa = make_uint4(0,0,0,0), qb = qa, qc = qa;
        if (k + 1 < NGRP) {
            int vn = t + 1024 * (k + 1);
            if (vn < n) {
                qa = pend_g[3 * (size_t)vn];
                qb = pend_g[3 * (size_t)vn + 1];
                qc = pend_g[3 * (size_t)vn + 2];
            }
        }

        const int np = (int)(pa.x & 0xffffu);
        const int e0 = pa.x >> 16;
        const int e1  = pa.y & 0xffff, e2  = pa.y >> 16;
        const int e3  = pa.z & 0xffff, e4  = pa.z >> 16;
        const int e5  = pa.w & 0xffff, e6  = pa.w >> 16;
        const int e7  = pb.x & 0xffff, e8  = pb.x >> 16;
        const int e9  = pb.y & 0xffff, e10 = pb.y >> 16;
        const int e11 = pb.z & 0xffff, e12 = pb.z >> 16;
        const int e13 = pb.w & 0xffff, e14 = pb.w >> 16;
        const int e15 = pc.x & 0xffff, e16 = pc.x >> 16;
        const int e17 = pc.y & 0xffff, e18 = pc.y >> 16;
        const int e19 = pc.z & 0xffff, e20 = pc.z >> 16;
        const int e21 = pc.w & 0xffff, e22 = pc.w >> 16;

        int my = (v < n) ? 0 : 2;
        int dvf = 0;
        const int* __restrict__ row = nbr + (size_t)v * (size_t)maxdeg;
        if (my == 0 && np > LCAP) dvf = deg[v];   // rare overflow

        int iter = 0;
        for (;;) {
            if (my == 0) {
                bool anyH = false; int undec = 0;
                if (np == 0) {
                    my = 1; st[v] = 1;
                } else if (np <= LCAP) {
                    // tier 1: up to 7 probes (independent batch)
                    {
                        int q0=st[e0], q1=st[e1], q2=st[e2], q3=st[e3];
                        int q4=st[e4], q5=st[e5], q6=st[e6];
                        if (np > 0) { anyH |= (q0 == 1); undec += (q0 == 0); }
                        if (np > 1) { anyH |= (q1 == 1); undec += (q1 == 0); }
                        if (np > 2) { anyH |= (q2 == 1); undec += (q2 == 0); }
                        if (np > 3) { anyH |= (q3 == 1); undec += (q3 == 0); }
                        if (np > 4) { anyH |= (q4 == 1); undec += (q4 == 0); }
                        if (np > 5) { anyH |= (q5 == 1); undec += (q5 == 0); }
                        if (np > 6) { anyH |= (q6 == 1); undec += (q6 == 0); }
                    }
                    if (np > 7) {    // tier 2: probes 7..14
                        int q7=st[e7],  q8=st[e8],  q9=st[e9],  q10=st[e10];
                        int q11=st[e11], q12=st[e12], q13=st[e13], q14=st[e14];
                        anyH |= (q7 == 1); undec += (q7 == 0);
                        if (np > 8)  { anyH |= (q8  == 1); undec += (q8  == 0); }
                        if (np > 9)  { anyH |= (q9  == 1); undec += (q9  == 0); }
                        if (np > 10) { anyH |= (q10 == 1); undec += (q10 == 0); }
                        if (np > 11) { anyH |= (q11 == 1); undec += (q11 == 0); }
                        if (np > 12) { anyH |= (q12 == 1); undec += (q12 == 0); }
                        if (np > 13) { anyH |= (q13 == 1); undec += (q13 == 0); }
                        if (np > 14) { anyH |= (q14 == 1); undec += (q14 == 0); }
                    }
                    if (np > 15) {   // tier 3: probes 15..22
                        int q15=st[e15], q16=st[e16], q17=st[e17], q18=st[e18];
                        int q19=st[e19], q20=st[e20], q21=st[e21], q22=st[e22];
                        anyH |= (q15 == 1); undec += (q15 == 0);
                        if (np > 16) { anyH |= (q16 == 1); undec += (q16 == 0); }
                        if (np > 17) { anyH |= (q17 == 1); undec += (q17 == 0); }
                        if (np > 18) { anyH |= (q18 == 1); undec += (q18 == 0); }
                        if (np > 19) { anyH |= (q19 == 1); undec += (q19 == 0); }
                        if (np > 20) { anyH |= (q20 == 1); undec += (q20 == 0); }
                        if (np > 21) { anyH |= (q21 == 1); undec += (q21 == 0); }
                        if (np > 22) { anyH |= (q22 == 1); undec += (q22 == 0); }
                    }
                } else {
                    // rare overflow: walk the sorted row prefix (bounded by dvf)
                    for (int kk = 0; kk < dvf; ++kk) {
                        int j = row[kk];
                        if (j >= v) break;           // sorted: prefix done
                        int q = st[j];
                        anyH |= (q == 1); undec += (q == 0);
                    }
                }
                if (my == 0) {
                    if (anyH)            { my = 2; st[v] = 2; }
                    else if (undec == 0) { my = 1; st[v] = 1; }
                }
            }
            if (__ballot(my == 0) == 0ULL) break;   // wave's 64 done -> advance
            CFENCE();                                // force LDS re-reads
            if (iter++ > 0) __builtin_amdgcn_s_sleep(1);  // don't hog LDS pipe
        }
        pa = qa; pb = qb; pc = qc;
    }

    __syncthreads();   // all waves done -> st final everywhere

    // ---- epilogue: count heads, scan, emit headlist / head_mask / count ----
    uint4 qq = ((const uint4*)st)[t];          // thread t owns bytes [16t,16t+16)
    int cnt = __popc(qq.x & 0x01010101u) + __popc(qq.y & 0x01010101u)
            + __popc(qq.z & 0x01010101u) + __popc(qq.w & 0x01010101u);
    int c = cnt;
    #pragma unroll
    for (int off = 1; off < 64; off <<= 1) {
        int x = __shfl_up(c, off);
        if (lane >= off) c += x;
    }
    if (lane == 63) s_ws[wid] = c;
    __syncthreads();
    int wexcl = 0, tot = 0;
    #pragma unroll
    for (int w = 0; w < TPB / 64; ++w) {
        int s = s_ws[w];
        tot += s;
        if (w < wid) wexcl += s;
    }
    int excl = wexcl + (c - cnt);
    #pragma unroll
    for (int i = 0; i < 16; ++i) {
        int v = t * 16 + i;
        if (st[v] == 1) { headlist[excl] = v; ++excl; }
    }
    for (int i = t; i < NV / 4; i += TPB) {
        unsigned w = ((const unsigned*)st)[i];
        float4 f;
        f.x = (float)(w & 1u);         f.y = (float)((w >> 8) & 1u);
        f.z = (float)((w >> 16) & 1u); f.w = (float)((w >> 24) & 1u);
        ((float4*)out_tail)[i] = f;
    }
    if (t == 0) out_tail[n] = (float)tot;
}

// ---------------------------------------------------------------------------
// K_avg (fused owner+avg): one 64-lane wave per output row.
// Rows are SORTED, so owner(j) = min adjacent head = FIRST head in row(j):
// walk row(j) from the front, break at the first head u; member iff u == h.
// Waves [tot,n): zero-fill the row (replaces the memset).
// ---------------------------------------------------------------------------
__global__ __launch_bounds__(256)
void k_avg(const float* __restrict__ vert, const int* __restrict__ nbr,
           const int* __restrict__ deg, int maxdeg, int n,
           const int* __restrict__ headlist,
           const float* __restrict__ tail, float* __restrict__ out)
{
    const int w    = (blockIdx.x * 256 + threadIdx.x) >> 6;
    const int lane = threadIdx.x & 63;
    if (w >= n) return;
    const int tot  = (int)tail[n];
    if (w >= tot) {
        reinterpret_cast<float4*>(out + (size_t)w * DD)[lane] = make_float4(0.f, 0.f, 0.f, 0.f);
        return;
    }
    const int h = headlist[w];

    const int dh = deg[h];
    const int* __restrict__ row = nbr + (size_t)h * (size_t)maxdeg;

    float4 acc = reinterpret_cast<const float4*>(vert + (size_t)h * DD)[lane];
    int cnt = 1;

    for (int k0 = 0; k0 < dh; k0 += 64) {
        int k = k0 + lane;
        int j = (k < dh) ? row[k] : -1;
        bool mem = false;
        if (j > h && tail[j] == 0.0f) {        // nonhead, higher candidate
            const int dj = deg[j];
            const int* __restrict__ rj = nbr + (size_t)j * (size_t)maxdeg;
            for (int kk = 0; kk < dj; ++kk) {
                int u = rj[kk];
                if (tail[u] != 0.0f) { mem = (u == h); break; }
            }
        }
        unsigned long long m = __ballot(mem);
        cnt += __popcll(m);
        while (m) {
            int bit = __ffsll((long long)m) - 1;
            m &= (m - 1);
            int jj = __shfl(j, bit);
            float4 rr = reinterpret_cast<const float4*>(vert + (size_t)jj * DD)[lane];
            acc.x += rr.x; acc.y += rr.y; acc.z += rr.z; acc.w += rr.w;
        }
    }
    const float inv = 1.0f / (float)cnt;
    float4 res;
    res.x = acc.x * inv; res.y = acc.y * inv;
    res.z = acc.z * inv; res.w = acc.w * inv;
    reinterpret_cast<float4*>(out + (size_t)w * DD)[lane] = res;
}

// ---------------------------------------------------------------------------
extern "C" void kernel_launch(void* const* d_in, const int* in_sizes, int n_in,
                              void* d_out, int out_size, void* d_ws, size_t ws_size,
                              hipStream_t stream)
{
    const float* vert = (const float*)d_in[0];
    const int*   nbr  = (const int*)d_in[1];
    const int*   deg  = (const int*)d_in[2];

    const int n      = in_sizes[2];            // 16384
    const int maxdeg = in_sizes[1] / n;
    const int d      = in_sizes[0] / n;        // 256

    int*   headlist = (int*)d_ws;                                  // n ints
    uint4* pend_g   = (uint4*)(headlist + n);                      // 3n uint4 (768KB)

    float* out      = (float*)d_out;
    float* out_tail = out + (size_t)n * (size_t)d;   // head_mask .. num_clusters

    hipLaunchKernelGGL(k_prep, dim3((n + 255) / 256), dim3(256), 0, stream,
                       nbr, deg, maxdeg, n, pend_g);

    hipLaunchKernelGGL(k_mis, dim3(1), dim3(TPB), 0, stream,
                       nbr, deg, maxdeg, n, pend_g, headlist, out_tail);

    const int blocks = (n * 64 + 255) / 256;   // one wave per output row
    hipLaunchKernelGGL(k_avg, dim3(blocks), dim3(256), 0, stream,
                       vert, nbr, deg, maxdeg, n, headlist, out_tail, out);
}

// Round 21
// 77.838 us; speedup vs baseline: 1.1298x; 1.1298x over previous
//
#include <hip/hip_runtime.h>
#include <cstdint>
#include <cstddef>

// Problem constants (from reference): N=16384, D=256.
#define NV 16384
#define DD 256
#define TPB 1024           // k_mis threads (16 waves), 1 vertex/thread/block
#define BLK 1024
#define PCAP 7             // in-block lower-neighbor cap (fallback exists)
#define HROW 24            // u16 slots per vertex in hi_g: [0]=count, [1..23]=higher nbrs
#define NPASS 512          // spin cap per barrier round (common case: 1 round/block)

// compiler memory barrier: forces LDS re-reads across passes WITHOUT ordering
// the loads within a pass against each other
#define CFENCE() asm volatile("" ::: "memory")

// ---------------------------------------------------------------------------
// K_prep (parallel): nbr rows are SORTED ascending (np.unique in the ref), so
// lower nbrs are a prefix and the in-block lower ones a contiguous subrange:
//   lo_b = first k with row[k] >= b ; nlo = first k with row[k] > v (== # lower)
// Packing loops then iterate ONLY the relevant short ranges (~9 avg vs 36).
//  - pend_g[v] (uint4): in-block lower nbrs (row[lo_b..nlo)) as u16 offsets
//  - hi_g[v*HROW..]: [count | 23 higher-nbr ids] (row[nlo..dv)), 3x uint4
// ---------------------------------------------------------------------------
__global__ __launch_bounds__(256)
void k_prep(const int* __restrict__ nbr, const int* __restrict__ deg,
            int maxdeg, int n, uint4* __restrict__ pend_g,
            unsigned short* __restrict__ hi_g)
{
    int v = blockIdx.x * 256 + threadIdx.x;
    if (v >= n) return;
    const int b  = v & ~(BLK - 1);
    const int dv = deg[v];
    const int* __restrict__ row = nbr + (size_t)v * (size_t)maxdeg;

    // split points in the sorted row (simple linear scans, predictable)
    int nlo = 0;
    while (nlo < dv && row[nlo] < v) ++nlo;
    int lo_b = nlo;
    while (lo_b > 0 && row[lo_b - 1] >= b) --lo_b;

    // pack in-block lower (short loop, <=7 normally)
    unsigned w0 = 0, w1 = 0, w2 = 0, w3 = 0;
    const int cnt = nlo - lo_b;
    {
        int m = cnt > PCAP ? PCAP : cnt;
        for (int i = 0; i < m; ++i) {
            unsigned val = (unsigned)(row[lo_b + i] - b);
            switch (i) {
                case 0: w0 |= val << 16; break;
                case 1: w1 |= val;       break;
                case 2: w1 |= val << 16; break;
                case 3: w2 |= val;       break;
                case 4: w2 |= val << 16; break;
                case 5: w3 |= val;       break;
                case 6: w3 |= val << 16; break;
            }
        }
    }
    // pack higher list (short loop, ~8 avg, <=23 stored)
    unsigned g0=0,g1=0,g2=0,g3=0,g4=0,g5=0,g6=0,g7=0,g8=0,g9=0,g10=0,g11=0;
    const int hic = dv - nlo;
    {
        int m = hic > HROW - 1 ? HROW - 1 : hic;
        for (int i = 0; i < m; ++i) {
            unsigned e = (unsigned)row[nlo + i];
            switch (i) {    // entry i at u16 slot 1+i: word (1+i)>>1, half (1+i)&1
                case 0:  g0  |= e << 16; break;
                case 1:  g1  |= e; break;   case 2:  g1  |= e << 16; break;
                case 3:  g2  |= e; break;   case 4:  g2  |= e << 16; break;
                case 5:  g3  |= e; break;   case 6:  g3  |= e << 16; break;
                case 7:  g4  |= e; break;   case 8:  g4  |= e << 16; break;
                case 9:  g5  |= e; break;   case 10: g5  |= e << 16; break;
                case 11: g6  |= e; break;   case 12: g6  |= e << 16; break;
                case 13: g7  |= e; break;   case 14: g7  |= e << 16; break;
                case 15: g8  |= e; break;   case 16: g8  |= e << 16; break;
                case 17: g9  |= e; break;   case 18: g9  |= e << 16; break;
                case 19: g10 |= e; break;   case 20: g10 |= e << 16; break;
                case 21: g11 |= e; break;   case 22: g11 |= e << 16; break;
            }
        }
    }
    g0 |= (unsigned)(hic > 0xffff ? 0xffff : hic);
    uint4* hq = (uint4*)(hi_g + (size_t)v * HROW);   // 48B rows, 16B-aligned
    hq[0] = make_uint4(g0, g1, g2, g3);
    hq[1] = make_uint4(g4, g5, g6, g7);
    hq[2] = make_uint4(g8, g9, g10, g11);
    w0 |= (unsigned)(cnt > 0xffff ? 0xffff : cnt);
    pend_g[v] = make_uint4(w0, w1, w2, w3);
}

// ---------------------------------------------------------------------------
// K_mis: lexicographic greedy MIS, single WG of 1024 threads (16 waves), PUSH.
// st: 0=unknown, 1=head, 2=nonhead (monotone -> LDS races benign).
// Waves spin until all their lanes are decided (in-block deps point strictly
// to lower indices -> provable progress), so a block needs ~ONE barrier.
// F-protocol kept as safety net (NPASS spin cap). 16-variant-validated floor:
// ~51.5us; probe style/count, pass count, phase count, barrier count, async
// dataflow all null or worse.
// ---------------------------------------------------------------------------
__global__ __launch_bounds__(TPB, 4)
void k_mis(const int* __restrict__ nbr, const int* __restrict__ deg,
           int maxdeg, int n,
           const uint4* __restrict__ pend_g, const unsigned short* __restrict__ hi_g,
           int* __restrict__ headlist, float* __restrict__ out_tail)
{
    __shared__ __align__(16) unsigned char st[NV];
    __shared__ int s_ws[TPB / 64];
    __shared__ int F[3];
    const int t    = threadIdx.x;
    const int lane = t & 63;
    const int wid  = t >> 6;

    ((uint4*)st)[t] = make_uint4(0u, 0u, 0u, 0u);   // 1024*16B == NV
    if (t < 3) F[t] = 0;
    __syncthreads();

    // prefetch block 0 (pend + hi row + deg), register double-buffered
    uint4 pv = make_uint4(0,0,0,0), h0 = pv, h1 = pv, h2 = pv;
    int   dv = 0;
    if (t < n) {
        pv = pend_g[t];
        const uint4* hp = (const uint4*)(hi_g + (size_t)t * HROW);
        h0 = hp[0]; h1 = hp[1]; h2 = hp[2];
        dv = deg[t];
    }
    int r = 0;

    for (int b = 0; b < n; b += BLK) {
        const int v = b + t;
        // prefetch next block; stays in flight across the drain-free barriers
        uint4 pn = make_uint4(0,0,0,0), n0 = pn, n1 = pn, n2 = pn;
        int   dn = 0;
        {
            int vn = b + BLK + t;
            if (vn < n) {
                pn = pend_g[vn];
                const uint4* hp = (const uint4*)(hi_g + (size_t)vn * HROW);
                n0 = hp[0]; n1 = hp[1]; n2 = hp[2];
                dn = deg[vn];
            }
        }

        const int np = pv.x & 0xffff;
        const int e0 = pv.x >> 16,    e1 = pv.y & 0xffff, e2 = pv.y >> 16;
        const int e3 = pv.z & 0xffff, e4 = pv.z >> 16;
        const int e5 = pv.w & 0xffff, e6 = pv.w >> 16;
        const int hic = (int)(h0.x & 0xffff);
        const int* __restrict__ row = nbr + (size_t)v * (size_t)maxdeg;

        int my = (v < n) ? 0 : 2;
        for (;; ++r) {
            if (t == 0) F[(r + 1) % 3] = 0;
            for (int pass = 0; pass < NPASS; ++pass) {
                if (my == 0) {
                    int qv = st[v];
                    int q0 = 0, q1 = 0, q2 = 0, q3 = 0, q4 = 0, q5 = 0, q6 = 0;
                    if (np > 0 && np <= PCAP) {
                        q0 = st[b + e0]; q1 = st[b + e1]; q2 = st[b + e2];
                        q3 = st[b + e3]; q4 = st[b + e4]; q5 = st[b + e5];
                        q6 = st[b + e6];
                    }
                    if (qv != 0) { my = 2; }
                    else {
                        bool anyH = false; int undec = 0;
                        if (np <= PCAP) {
                            if (np > 0) { anyH |= (q0 == 1); undec += (q0 == 0); }
                            if (np > 1) { anyH |= (q1 == 1); undec += (q1 == 0); }
                            if (np > 2) { anyH |= (q2 == 1); undec += (q2 == 0); }
                            if (np > 3) { anyH |= (q3 == 1); undec += (q3 == 0); }
                            if (np > 4) { anyH |= (q4 == 1); undec += (q4 == 0); }
                            if (np > 5) { anyH |= (q5 == 1); undec += (q5 == 0); }
                            if (np > 6) { anyH |= (q6 == 1); undec += (q6 == 0); }
                        } else {
                            for (int k = 0; k < dv; ++k) {
                                int j = row[k];
                                if (j >= b && j < v) {
                                    int q = st[j];
                                    anyH |= (q == 1); undec += (q == 0);
                                }
                            }
                        }
                        if (anyH) { my = 2; st[v] = 2; }
                        else if (undec == 0) {
                            my = 1;
                            st[v] = 1;
                            if (hic <= HROW - 1) {
                                #define PUSHE(word, sh, k) if ((k) < hic) st[((word) >> (sh)) & 0xffffu] = 2
                                PUSHE(h0.x,16, 0); PUSHE(h0.y, 0, 1); PUSHE(h0.y,16, 2);
                                PUSHE(h0.z, 0, 3); PUSHE(h0.z,16, 4); PUSHE(h0.w, 0, 5);
                                PUSHE(h0.w,16, 6);
                                PUSHE(h1.x, 0, 7); PUSHE(h1.x,16, 8); PUSHE(h1.y, 0, 9);
                                PUSHE(h1.y,16,10); PUSHE(h1.z, 0,11); PUSHE(h1.z,16,12);
                                PUSHE(h1.w, 0,13); PUSHE(h1.w,16,14);
                                PUSHE(h2.x, 0,15); PUSHE(h2.x,16,16); PUSHE(h2.y, 0,17);
                                PUSHE(h2.y,16,18); PUSHE(h2.z, 0,19); PUSHE(h2.z,16,20);
                                PUSHE(h2.w, 0,21); PUSHE(h2.w,16,22);
                                #undef PUSHE
                            } else {
                                for (int k = 0; k < dv; ++k) {
                                    int j = row[k];
                                    if (j > v) st[j] = 2;
                                }
                            }
                        }
                    }
                }
                if (__ballot(my == 0) == 0ULL) break;   // wave done -> barrier
                CFENCE();   // force genuine LDS re-reads next pass
            }
            if (my == 0) F[r % 3] = 1;   // only if spin cap was exhausted
            // drain-free barrier: LDS visible, global prefetch stays in flight
            asm volatile("s_waitcnt lgkmcnt(0)\n\ts_barrier" ::: "memory");
            if (F[r % 3] == 0) { ++r; break; }
        }
        pv = pn; h0 = n0; h1 = n1; h2 = n2; dv = dn;
    }

    // ---- epilogue: count heads, scan, emit headlist / head_mask / count ----
    uint4 qq = ((const uint4*)st)[t];          // thread t owns bytes [16t,16t+16)
    int cnt = __popc(qq.x & 0x01010101u) + __popc(qq.y & 0x01010101u)
            + __popc(qq.z & 0x01010101u) + __popc(qq.w & 0x01010101u);
    int c = cnt;
    #pragma unroll
    for (int off = 1; off < 64; off <<= 1) {
        int x = __shfl_up(c, off);
        if (lane >= off) c += x;
    }
    if (lane == 63) s_ws[wid] = c;
    __syncthreads();
    int wexcl = 0, tot = 0;
    #pragma unroll
    for (int w = 0; w < TPB / 64; ++w) {
        int s = s_ws[w];
        tot += s;
        if (w < wid) wexcl += s;
    }
    int excl = wexcl + (c - cnt);
    #pragma unroll
    for (int i = 0; i < 16; ++i) {
        int v = t * 16 + i;
        if (st[v] == 1) { headlist[excl] = v; ++excl; }
    }
    for (int i = t; i < NV / 4; i += TPB) {
        unsigned w = ((const unsigned*)st)[i];
        float4 f;
        f.x = (float)(w & 1u);         f.y = (float)((w >> 8) & 1u);
        f.z = (float)((w >> 16) & 1u); f.w = (float)((w >> 24) & 1u);
        ((float4*)out_tail)[i] = f;
    }
    if (t == 0) out_tail[n] = (float)tot;
}

// ---------------------------------------------------------------------------
// K_avg (fused owner+avg): one 64-lane wave per output row.
// Rows are SORTED, so owner(j) = min adjacent head = FIRST head in row(j):
// walk row(j) from the front, break at the first head u; member iff u == h.
// Waves [tot,n): zero-fill the row (replaces the memset).
// ---------------------------------------------------------------------------
__global__ __launch_bounds__(256)
void k_avg(const float* __restrict__ vert, const int* __restrict__ nbr,
           const int* __restrict__ deg, int maxdeg, int n,
           const int* __restrict__ headlist,
           const float* __restrict__ tail, float* __restrict__ out)
{
    const int w    = (blockIdx.x * 256 + threadIdx.x) >> 6;
    const int lane = threadIdx.x & 63;
    if (w >= n) return;
    const int tot  = (int)tail[n];
    if (w >= tot) {
        reinterpret_cast<float4*>(out + (size_t)w * DD)[lane] = make_float4(0.f, 0.f, 0.f, 0.f);
        return;
    }
    const int h = headlist[w];

    const int dh = deg[h];
    const int* __restrict__ row = nbr + (size_t)h * (size_t)maxdeg;

    float4 acc = reinterpret_cast<const float4*>(vert + (size_t)h * DD)[lane];
    int cnt = 1;

    for (int k0 = 0; k0 < dh; k0 += 64) {
        int k = k0 + lane;
        int j = (k < dh) ? row[k] : -1;
        bool mem = false;
        if (j > h && tail[j] == 0.0f) {        // nonhead, higher candidate
            // owner test: first head in j's sorted row must be h
            const int dj = deg[j];
            const int* __restrict__ rj = nbr + (size_t)j * (size_t)maxdeg;
            for (int kk = 0; kk < dj; ++kk) {
                int u = rj[kk];
                if (tail[u] != 0.0f) { mem = (u == h); break; }
            }
        }
        unsigned long long m = __ballot(mem);
        cnt += __popcll(m);
        while (m) {
            int bit = __ffsll((long long)m) - 1;
            m &= (m - 1);
            int jj = __shfl(j, bit);
            float4 rr = reinterpret_cast<const float4*>(vert + (size_t)jj * DD)[lane];
            acc.x += rr.x; acc.y += rr.y; acc.z += rr.z; acc.w += rr.w;
        }
    }
    const float inv = 1.0f / (float)cnt;
    float4 res;
    res.x = acc.x * inv; res.y = acc.y * inv;
    res.z = acc.z * inv; res.w = acc.w * inv;
    reinterpret_cast<float4*>(out + (size_t)w * DD)[lane] = res;
}

// ---------------------------------------------------------------------------
extern "C" void kernel_launch(void* const* d_in, const int* in_sizes, int n_in,
                              void* d_out, int out_size, void* d_ws, size_t ws_size,
                              hipStream_t stream)
{
    const float* vert = (const float*)d_in[0];
    const int*   nbr  = (const int*)d_in[1];
    const int*   deg  = (const int*)d_in[2];

    const int n      = in_sizes[2];            // 16384
    const int maxdeg = in_sizes[1] / n;
    const int d      = in_sizes[0] / n;        // 256

    int*   headlist = (int*)d_ws;                                  // n ints
    uint4* pend_g   = (uint4*)(headlist + n);                      // n uint4 (256KB)
    unsigned short* hi_g = (unsigned short*)(pend_g + n);          // n * HROW u16

    float* out      = (float*)d_out;
    float* out_tail = out + (size_t)n * (size_t)d;   // head_mask .. num_clusters

    hipLaunchKernelGGL(k_prep, dim3((n + 255) / 256), dim3(256), 0, stream,
                       nbr, deg, maxdeg, n, pend_g, hi_g);

    hipLaunchKernelGGL(k_mis, dim3(1), dim3(TPB), 0, stream,
                       nbr, deg, maxdeg, n, pend_g, hi_g, headlist, out_tail);

    const int blocks = (n * 64 + 255) / 256;   // one wave per output row
    hipLaunchKernelGGL(k_avg, dim3(blocks), dim3(256), 0, stream,
                       vert, nbr, deg, maxdeg, n, headlist, out_tail, out);
}